// Round 1
// baseline (207.411 us; speedup 1.0000x reference)
//
#include <hip/hip_runtime.h>
#include <stdint.h>
#include <stddef.h>

// Problem constants
#define HOUT 64
#define WOUT 64
#define CIN  32
#define COUT 16
#define BATCH 64
#define SLOC 4096          // HOUT*WOUT
#define KTOT 288           // CIN*9
#define HPAD 66            // 64 + 2 pad
// Padded-X pixel block = BATCH*CIN bf16 = 2048 ushorts = 4096 bytes

typedef __attribute__((ext_vector_type(8))) short  short8;   // 8 bf16 (4 VGPRs)
typedef __attribute__((ext_vector_type(4))) float  floatx4;  // MFMA acc

// fp32 -> bf16 round-to-nearest-even (bit pattern)
static __device__ __forceinline__ unsigned short f2bf(float f) {
    union { float f; unsigned int u; } v; v.f = f;
    unsigned int u = v.u;
    unsigned int r = (u + 0x7FFFu + ((u >> 16) & 1u)) >> 16;
    return (unsigned short)r;
}

// Zero the padded border of Xt: 260 border pixels, 4096B each.
// 260 blocks x 256 threads, one uint4 (16B) store per thread.
__global__ __launch_bounds__(256) void zero_border_kernel(unsigned short* __restrict__ xt) {
    int bid = blockIdx.x;
    int h1, w1;
    if (bid < 66)       { h1 = 0;  w1 = bid; }
    else if (bid < 132) { h1 = 65; w1 = bid - 66; }
    else { int r = bid - 132; h1 = (r >> 1) + 1; w1 = (r & 1) ? 65 : 0; }
    uint4* dst = (uint4*)(xt + (size_t)(h1 * HPAD + w1) * 2048);
    dst[threadIdx.x] = uint4{0u, 0u, 0u, 0u};
}

// Transpose X[b][c][h][w] fp32 -> Xt[(h+1)][(w+1)][b][c] bf16 via LDS.
// grid = (64 h-rows, 8 b-tiles of 8), 256 threads.
__global__ __launch_bounds__(256) void transpose_kernel(const float* __restrict__ X,
                                                        unsigned short* __restrict__ xt) {
    __shared__ unsigned short lds[64 * 8 * 32]; // [w][b'][c], 32KB
    int h  = blockIdx.x;    // 0..63
    int bt = blockIdx.y;    // 0..7  (b-tile of 8 batches)
    int t  = threadIdx.x;

    // Load 8b' x 32c x 64w floats, coalesced float4 along w.
    for (int i = 0; i < 16; ++i) {
        int idx = t + i * 256;            // 0..4095
        int bp  = idx >> 9;               // 0..7
        int c   = (idx >> 4) & 31;        // 0..31
        int w4  = idx & 15;               // 0..15
        const floatx4 v = *(const floatx4*)(
            X + ((((size_t)(bt * 8 + bp)) * CIN + c) * HOUT + h) * WOUT + (size_t)w4 * 4);
#pragma unroll
        for (int e = 0; e < 4; ++e)
            lds[(((w4 * 4 + e) * 8) + bp) * 32 + c] = f2bf(v[e]);
    }
    __syncthreads();

    // Store: per w, a contiguous 512B [b'][c] chunk into the pixel block.
    const uint4* src = (const uint4*)lds;
    for (int i = 0; i < 8; ++i) {
        int idx = t + i * 256;            // 0..2047
        int w   = idx >> 5;
        int x4  = idx & 31;
        *(uint4*)((char*)xt + (size_t)((h + 1) * HPAD + (w + 1)) * 4096
                            + (size_t)bt * 512 + (size_t)x4 * 16) = src[idx];
    }
}

// Main: one workgroup per spatial site s. 4 waves cover b-tiles 0..3 (16 each).
// Per wave: out[16b x 16c_out] = sum over 9 taps of MFMA 16x16x32 (K=32 channels).
// A (u) from padded Xt (16B contiguous/lane); B (W) gathered fp32->bf16;
// colsum(W) accumulated in fp32 for the bias term.
__global__ __launch_bounds__(256) void varconv_kernel(const unsigned short* __restrict__ xt,
                                                      const float* __restrict__ Wg,
                                                      const float* __restrict__ bias,
                                                      float* __restrict__ out) {
    int s = blockIdx.x;
    int y = s >> 6, x = s & 63;
    int lane = threadIdx.x & 63;
    int wv   = threadIdx.x >> 6;
    int q = lane >> 4;          // quad
    int n = lane & 15;          // = c_out for B/D, = b-within-tile for A
    int b0 = wv * 16;

    floatx4 acc = {0.f, 0.f, 0.f, 0.f};
    float csum = 0.f;

    // W[s][k][c_out]: lane covers c_in = 8q+j across taps t: k = (8q+j)*9 + t
    const float* wbase = Wg + (size_t)s * (KTOT * COUT) + (size_t)(8 * q) * 9 * COUT + n;
    // Xt pixel block: [b][c] bf16; lane reads b = b0+n, c = 8q..8q+7 (16B)
    const unsigned short* abase = xt + (size_t)(b0 + n) * CIN + (size_t)q * 8;

#pragma unroll
    for (int t = 0; t < 9; ++t) {
        const int cy = t / 3, cx = t % 3;                 // compile-time
        int pix = (y + cy) * HPAD + (x + cx);             // padded coords
        short8 afrag = *(const short8*)(abase + (size_t)pix * 2048);

        float w8[8];
#pragma unroll
        for (int j = 0; j < 8; ++j)
            w8[j] = wbase[(size_t)(j * 9 + t) * COUT];

        short8 bfrag;
#pragma unroll
        for (int j = 0; j < 8; ++j) {
            csum += w8[j];
            bfrag[j] = (short)f2bf(w8[j]);
        }
        acc = __builtin_amdgcn_mfma_f32_16x16x32_bf16(afrag, bfrag, acc, 0, 0, 0);
    }

    // Full colsum[c_out]: reduce partials across the 4 quads.
    csum += __shfl_xor(csum, 16, 64);
    csum += __shfl_xor(csum, 32, 64);
    float badd = bias[s] * csum;

    // D: col = lane&15 = c_out, row = 4q+r = b-within-tile.
#pragma unroll
    for (int r = 0; r < 4; ++r) {
        int b = b0 + 4 * q + r;
        out[((size_t)b * COUT + n) * SLOC + s] = acc[r] + badd;
    }
}

extern "C" void kernel_launch(void* const* d_in, const int* in_sizes, int n_in,
                              void* d_out, int out_size, void* d_ws, size_t ws_size,
                              hipStream_t stream) {
    const float* X    = (const float*)d_in[0];   // [64][32][64][64] fp32
    const float* Wg   = (const float*)d_in[1];   // [4096][288][16] fp32
    const float* bias = (const float*)d_in[2];   // [4096] fp32
    float* out = (float*)d_out;                  // [64][16][4096] fp32

    // Workspace: padded bf16 X-transpose, 66*66*64*32*2 = 17,842,176 bytes
    unsigned short* xt = (unsigned short*)d_ws;

    zero_border_kernel<<<260, 256, 0, stream>>>(xt);
    transpose_kernel<<<dim3(64, 8), 256, 0, stream>>>(X, xt);
    varconv_kernel<<<SLOC, 256, 0, stream>>>(xt, Wg, bias, out);
}

// Round 2
// 176.323 us; speedup vs baseline: 1.1763x; 1.1763x over previous
//
#include <hip/hip_runtime.h>
#include <stdint.h>
#include <stddef.h>

// Problem constants
#define HOUT 64
#define WOUT 64
#define CIN  32
#define COUT 16
#define BATCH 64
#define SLOC 4096          // HOUT*WOUT
#define KTOT 288           // CIN*9
#define HPAD 66            // 64 + 2 pad
// Padded-X pixel block = BATCH*CIN bf16 = 2048 ushorts = 4096 bytes

typedef __attribute__((ext_vector_type(8))) short  short8;   // 8 bf16 (4 VGPRs)
typedef __attribute__((ext_vector_type(4))) float  floatx4;  // MFMA acc / float4

// fp32 -> bf16 round-to-nearest-even (bit pattern)
static __device__ __forceinline__ unsigned short f2bf(float f) {
    union { float f; unsigned int u; } v; v.f = f;
    unsigned int u = v.u;
    unsigned int r = (u + 0x7FFFu + ((u >> 16) & 1u)) >> 16;
    return (unsigned short)r;
}

// Zero the padded border of Xt: 260 border pixels, 4096B each.
__global__ __launch_bounds__(256) void zero_border_kernel(unsigned short* __restrict__ xt) {
    int bid = blockIdx.x;
    int h1, w1;
    if (bid < 66)       { h1 = 0;  w1 = bid; }
    else if (bid < 132) { h1 = 65; w1 = bid - 66; }
    else { int r = bid - 132; h1 = (r >> 1) + 1; w1 = (r & 1) ? 65 : 0; }
    uint4* dst = (uint4*)(xt + (size_t)(h1 * HPAD + w1) * 2048);
    dst[threadIdx.x] = uint4{0u, 0u, 0u, 0u};
}

// Transpose X[b][c][h][w] fp32 -> Xt[(h+1)][(w+1)][b][c] bf16. LDS-free.
// grid = (64 h, 64 b), 256 threads; thread t: w = t>>2, cgroup = t&3 (8 channels).
// Reads: 8 coalesced dword loads (per instr: 4 channels x 16 w = 4 full lines).
// Writes: one uint4/thread; 4 consecutive lanes (cg 0..3) cover one full 64B line
// (all 32 c of one (h,w,b)) -> no partial-line HBM writes.
__global__ __launch_bounds__(256) void transpose_kernel(const float* __restrict__ X,
                                                        unsigned short* __restrict__ xt) {
    int h = blockIdx.x;
    int b = blockIdx.y;
    int t = threadIdx.x;
    int w  = t >> 2;        // 0..63
    int cg = t & 3;         // 0..3  (channels cg*8 .. cg*8+7)

    const float* xb = X + (((size_t)b * CIN + cg * 8) * HOUT + h) * WOUT + w;
    unsigned short v[8];
#pragma unroll
    for (int j = 0; j < 8; ++j)
        v[j] = f2bf(xb[(size_t)j * HOUT * WOUT]);

    uint4 pack;
    pack.x = (unsigned)v[0] | ((unsigned)v[1] << 16);
    pack.y = (unsigned)v[2] | ((unsigned)v[3] << 16);
    pack.z = (unsigned)v[4] | ((unsigned)v[5] << 16);
    pack.w = (unsigned)v[6] | ((unsigned)v[7] << 16);

    *(uint4*)(xt + (size_t)((h + 1) * HPAD + (w + 1)) * 2048 + b * CIN + cg * 8) = pack;
}

// Main kernel. Workgroup = 16 consecutive sites (one 64B out-line per (b,c)) x
// half the batch (32 b). Grid 512 = 2 blocks/CU. Block-id swizzle pairs the two
// batch-halves of one site-group 8 ids apart -> same XCD -> W_s read hits L2.
// Wave wv: sites sl = 4wv..4wv+3, m-tiles mt=0,1 (b = B0+16mt+..).
// Results staged in LDS [c][sl][b] (b-chunks XOR-swizzled by c) then written as
// full-line float4 stores (4 consecutive lanes = 64B line in s).
__global__ __launch_bounds__(256) void varconv_kernel(const unsigned short* __restrict__ xt,
                                                      const float* __restrict__ Wg,
                                                      const float* __restrict__ bias,
                                                      float* __restrict__ out) {
    __shared__ float lds[16 * 16 * 32];   // [c][sl][b] floats, 32 KB

    int id = blockIdx.x;
    int g  = ((id >> 4) << 3) | (id & 7);   // site-group 0..255
    int hh = (id >> 3) & 1;                 // batch half
    int s0 = g * 16;
    int y  = s0 >> 6;
    int x0 = s0 & 63;
    int B0 = hh * 32;

    int lane = threadIdx.x & 63, wv = threadIdx.x >> 6;
    int q = lane >> 4;          // quad
    int n = lane & 15;          // = c_out (B/D), = b-within-tile (A)

#pragma unroll
    for (int i = 0; i < 4; ++i) {
        int sl = wv * 4 + i;
        int s  = s0 + sl;
        int x  = x0 + sl;

        // --- W fragments for this site: lane covers c_in = 8q+j, taps t ---
        const float* wb = Wg + (size_t)s * (KTOT * COUT) + (size_t)(8 * q) * 9 * COUT + n;
        short8 bf[9];
        float csum = 0.f;
#pragma unroll
        for (int t = 0; t < 9; ++t) {
            float w8[8];
#pragma unroll
            for (int j = 0; j < 8; ++j)
                w8[j] = wb[(size_t)(j * 9 + t) * COUT];
#pragma unroll
            for (int j = 0; j < 8; ++j) {
                csum += w8[j];
                bf[t][j] = (short)f2bf(w8[j]);
            }
        }
        csum += __shfl_xor(csum, 16, 64);
        csum += __shfl_xor(csum, 32, 64);
        float badd = bias[s] * csum;     // ufld = u + bias  =>  out += bias*colsum(W)

        // --- two 16-batch m-tiles ---
#pragma unroll
        for (int mt = 0; mt < 2; ++mt) {
            const unsigned short* ab = xt + (size_t)(B0 + mt * 16 + n) * CIN + q * 8;
            floatx4 acc = {0.f, 0.f, 0.f, 0.f};
#pragma unroll
            for (int t = 0; t < 9; ++t) {
                const int cy = t / 3, cx = t % 3;
                int pix = (y + cy) * HPAD + (x + cx);
                short8 af = *(const short8*)(ab + (size_t)pix * 2048);
                acc = __builtin_amdgcn_mfma_f32_16x16x32_bf16(af, bf[t], acc, 0, 0, 0);
            }
            // D: col = n = c_out, row(b-within-tile) = 4q+r
            int bcl   = mt * 4 + q;             // local b-chunk 0..7
            int chunk = bcl ^ (n & 7);          // swizzle -> conflict-free b128
            floatx4 v = {acc[0] + badd, acc[1] + badd, acc[2] + badd, acc[3] + badd};
            *(floatx4*)&lds[n * 512 + sl * 32 + chunk * 4] = v;
        }
    }

    __syncthreads();

    // --- epilogue: full-line coalesced writes ---
    int c   = lane >> 2;     // 0..15
    int slg = lane & 3;      // 0..3  (s-subgroup of 4)
#pragma unroll
    for (int it = 0; it < 2; ++it) {
        int bcl   = wv + 4 * it;            // local b-chunk 0..7
        int chunk = bcl ^ (c & 7);
        floatx4 vj[4];
#pragma unroll
        for (int j = 0; j < 4; ++j) {
            int sl = slg * 4 + j;
            vj[j] = *(floatx4*)&lds[c * 512 + sl * 32 + chunk * 4];
        }
#pragma unroll
        for (int i2 = 0; i2 < 4; ++i2) {
            int b = B0 + bcl * 4 + i2;
            floatx4 o = {vj[0][i2], vj[1][i2], vj[2][i2], vj[3][i2]};
            // 4 consecutive lanes (slg 0..3) cover s0..s0+15 = one 64B line
            *(floatx4*)(out + ((size_t)(b * COUT + c)) * SLOC + s0 + slg * 4) = o;
        }
    }
}

extern "C" void kernel_launch(void* const* d_in, const int* in_sizes, int n_in,
                              void* d_out, int out_size, void* d_ws, size_t ws_size,
                              hipStream_t stream) {
    const float* X    = (const float*)d_in[0];   // [64][32][64][64] fp32
    const float* Wg   = (const float*)d_in[1];   // [4096][288][16] fp32
    const float* bias = (const float*)d_in[2];   // [4096] fp32
    float* out = (float*)d_out;                  // [64][16][4096] fp32

    unsigned short* xt = (unsigned short*)d_ws;  // 66*66*64*32*2 = 17.8 MB

    zero_border_kernel<<<260, 256, 0, stream>>>(xt);
    transpose_kernel<<<dim3(64, 64), 256, 0, stream>>>(X, xt);
    varconv_kernel<<<512, 256, 0, stream>>>(xt, Wg, bias, out);
}

// Round 3
// 173.812 us; speedup vs baseline: 1.1933x; 1.0145x over previous
//
#include <hip/hip_runtime.h>
#include <stdint.h>
#include <stddef.h>

// Problem constants
#define HOUT 64
#define WOUT 64
#define CIN  32
#define COUT 16
#define BATCH 64
#define SLOC 4096          // HOUT*WOUT
#define KTOT 288           // CIN*9
#define HPAD 66            // 64 + 2 pad
// Padded-X pixel block = BATCH*CIN bf16 = 2048 ushorts = 4096 bytes

typedef __attribute__((ext_vector_type(8))) short  short8;   // 8 bf16 (4 VGPRs)
typedef __attribute__((ext_vector_type(4))) float  floatx4;  // MFMA acc / float4

// fp32 -> bf16 round-to-nearest-even (bit pattern)
static __device__ __forceinline__ unsigned short f2bf(float f) {
    union { float f; unsigned int u; } v; v.f = f;
    unsigned int u = v.u;
    unsigned int r = (u + 0x7FFFu + ((u >> 16) & 1u)) >> 16;
    return (unsigned short)r;
}

// Zero the padded border of Xt: 260 border pixels, 4096B each.
__global__ __launch_bounds__(256) void zero_border_kernel(unsigned short* __restrict__ xt) {
    int bid = blockIdx.x;
    int h1, w1;
    if (bid < 66)       { h1 = 0;  w1 = bid; }
    else if (bid < 132) { h1 = 65; w1 = bid - 66; }
    else { int r = bid - 132; h1 = (r >> 1) + 1; w1 = (r & 1) ? 65 : 0; }
    uint4* dst = (uint4*)(xt + (size_t)(h1 * HPAD + w1) * 2048);
    dst[threadIdx.x] = uint4{0u, 0u, 0u, 0u};
}

// Transpose X[b][c][h][w] fp32 -> Xt[(h+1)][(w+1)][b][c] bf16. LDS-free.
// grid = (64 h, 64 b), 256 threads; thread t: w = t>>2, cgroup = t&3 (8 channels).
__global__ __launch_bounds__(256) void transpose_kernel(const float* __restrict__ X,
                                                        unsigned short* __restrict__ xt) {
    int h = blockIdx.x;
    int b = blockIdx.y;
    int t = threadIdx.x;
    int w  = t >> 2;        // 0..63
    int cg = t & 3;         // 0..3  (channels cg*8 .. cg*8+7)

    const float* xb = X + (((size_t)b * CIN + cg * 8) * HOUT + h) * WOUT + w;
    unsigned short v[8];
#pragma unroll
    for (int j = 0; j < 8; ++j)
        v[j] = f2bf(xb[(size_t)j * HOUT * WOUT]);

    uint4 pack;
    pack.x = (unsigned)v[0] | ((unsigned)v[1] << 16);
    pack.y = (unsigned)v[2] | ((unsigned)v[3] << 16);
    pack.z = (unsigned)v[4] | ((unsigned)v[5] << 16);
    pack.w = (unsigned)v[6] | ((unsigned)v[7] << 16);

    *(uint4*)(xt + (size_t)((h + 1) * HPAD + (w + 1)) * 2048 + b * CIN + cg * 8) = pack;
}

// Main kernel. Block = 16 consecutive sites x 16 batches (quarter). Grid 1024 =
// 4 blocks/CU (16 waves/CU). The 4 batch-quarter blocks of a site-group get ids
// == lo (mod 8) within a 24-id window -> same XCD, co-resident -> W HBM-fetched
// once, 3 L2 hits. launch_bounds(256,4): VGPR cap 128 so all 72 W dwords per
// site can be in flight (R2 failure mode: VGPR=60 -> serialized load batches).
__global__ __launch_bounds__(256, 4) void varconv_kernel(const unsigned short* __restrict__ xt,
                                                         const float* __restrict__ Wg,
                                                         const float* __restrict__ bias,
                                                         float* __restrict__ out) {
    __shared__ float lds[16 * 16 * 16];   // [c][sl][b-slots], 16 KB

    int id = blockIdx.x;
    int lo = id & 7;                       // XCD
    int q4 = (id >> 3) & 3;                // batch quarter
    int g  = ((id >> 5) << 3) | lo;        // site-group 0..255
    int s0 = g * 16;
    int y  = s0 >> 6;
    int x0 = s0 & 63;
    int B0 = q4 * 16;

    int lane = threadIdx.x & 63, wv = threadIdx.x >> 6;
    int q = lane >> 4;          // quad
    int n = lane & 15;          // = c_out (B/D), = b-within-tile (A)

#pragma unroll
    for (int i = 0; i < 4; ++i) {
        int sl = wv * 4 + i;
        int s  = s0 + sl;
        int x  = x0 + sl;

        // --- issue ALL 72 W loads for this site before any use ---
        const float* wb = Wg + (size_t)s * (KTOT * COUT) + (size_t)(8 * q) * 9 * COUT + n;
        float w[9][8];
#pragma unroll
        for (int t = 0; t < 9; ++t)
#pragma unroll
            for (int j = 0; j < 8; ++j)
                w[t][j] = wb[(size_t)(j * 9 + t) * COUT];

        float csum = 0.f;
        short8 bf[9];
#pragma unroll
        for (int t = 0; t < 9; ++t)
#pragma unroll
            for (int j = 0; j < 8; ++j) {
                csum += w[t][j];
                bf[t][j] = (short)f2bf(w[t][j]);
            }
        csum += __shfl_xor(csum, 16, 64);
        csum += __shfl_xor(csum, 32, 64);
        float badd = bias[s] * csum;     // ufld = u + bias  =>  out += bias*colsum(W)

        // --- one 16-batch m-tile ---
        const unsigned short* ab = xt + (size_t)(B0 + n) * CIN + q * 8;
        floatx4 acc = {0.f, 0.f, 0.f, 0.f};
#pragma unroll
        for (int t = 0; t < 9; ++t) {
            const int cy = t / 3, cx = t % 3;
            int pix = (y + cy) * HPAD + (x + cx);
            short8 af = *(const short8*)(ab + (size_t)pix * 2048);
            acc = __builtin_amdgcn_mfma_f32_16x16x32_bf16(af, bf[t], acc, 0, 0, 0);
        }
        // D: col = n = c_out, row(b local) = 4q+r. Slot-XOR for conflict-free b128.
        int slot = q ^ (n & 3);
        floatx4 v = {acc[0] + badd, acc[1] + badd, acc[2] + badd, acc[3] + badd};
        *(floatx4*)&lds[n * 256 + sl * 16 + slot * 4] = v;
    }

    __syncthreads();

    // --- epilogue: full-line coalesced writes (4 lanes = one 64B line) ---
    int c   = lane >> 2;     // 0..15
    int slg = lane & 3;      // 0..3
#pragma unroll
    for (int i2 = 0; i2 < 4; ++i2) {
        int ib   = wv * 4 + i2;             // local b 0..15
        int slot = (ib >> 2) ^ (c & 3);
        float o0[4];
#pragma unroll
        for (int e = 0; e < 4; ++e)
            o0[e] = lds[c * 256 + (slg * 4 + e) * 16 + slot * 4 + (ib & 3)];
        floatx4 o = {o0[0], o0[1], o0[2], o0[3]};
        *(floatx4*)(out + ((size_t)((B0 + ib) * COUT + c)) * SLOC + s0 + slg * 4) = o;
    }
}

extern "C" void kernel_launch(void* const* d_in, const int* in_sizes, int n_in,
                              void* d_out, int out_size, void* d_ws, size_t ws_size,
                              hipStream_t stream) {
    const float* X    = (const float*)d_in[0];   // [64][32][64][64] fp32
    const float* Wg   = (const float*)d_in[1];   // [4096][288][16] fp32
    const float* bias = (const float*)d_in[2];   // [4096] fp32
    float* out = (float*)d_out;                  // [64][16][4096] fp32

    unsigned short* xt = (unsigned short*)d_ws;  // 66*66*64*32*2 = 17.8 MB

    zero_border_kernel<<<260, 256, 0, stream>>>(xt);
    transpose_kernel<<<dim3(64, 64), 256, 0, stream>>>(X, xt);
    varconv_kernel<<<1024, 256, 0, stream>>>(xt, Wg, bias, out);
}

// Round 4
// 166.939 us; speedup vs baseline: 1.2424x; 1.0412x over previous
//
#include <hip/hip_runtime.h>
#include <stdint.h>
#include <stddef.h>

// Problem constants
#define HOUT 64
#define WOUT 64
#define CIN  32
#define COUT 16
#define BATCH 64
#define SLOC 4096          // HOUT*WOUT
#define KTOT 288           // CIN*9
#define HPAD 66            // 64 + 2 pad
// Padded-X pixel block = BATCH*CIN bf16 = 2048 ushorts = 4096 bytes

typedef __attribute__((ext_vector_type(8))) short  short8;   // 8 bf16 (4 VGPRs)
typedef __attribute__((ext_vector_type(4))) float  floatx4;  // MFMA acc / float4

// fp32 -> bf16 round-to-nearest-even (bit pattern)
static __device__ __forceinline__ unsigned short f2bf(float f) {
    union { float f; unsigned int u; } v; v.f = f;
    unsigned int u = v.u;
    unsigned int r = (u + 0x7FFFu + ((u >> 16) & 1u)) >> 16;
    return (unsigned short)r;
}

// Zero the padded border of Xt: 260 border pixels, 4096B each.
__global__ __launch_bounds__(256) void zero_border_kernel(unsigned short* __restrict__ xt) {
    int bid = blockIdx.x;
    int h1, w1;
    if (bid < 66)       { h1 = 0;  w1 = bid; }
    else if (bid < 132) { h1 = 65; w1 = bid - 66; }
    else { int r = bid - 132; h1 = (r >> 1) + 1; w1 = (r & 1) ? 65 : 0; }
    uint4* dst = (uint4*)(xt + (size_t)(h1 * HPAD + w1) * 2048);
    dst[threadIdx.x] = uint4{0u, 0u, 0u, 0u};
}

// Transpose X[b][c][h][w] fp32 -> Xt[(h+1)][(w+1)][b][c] bf16. LDS-free.
__global__ __launch_bounds__(256) void transpose_kernel(const float* __restrict__ X,
                                                        unsigned short* __restrict__ xt) {
    int h = blockIdx.x;
    int b = blockIdx.y;
    int t = threadIdx.x;
    int w  = t >> 2;        // 0..63
    int cg = t & 3;         // 0..3  (channels cg*8 .. cg*8+7)

    const float* xb = X + (((size_t)b * CIN + cg * 8) * HOUT + h) * WOUT + w;
    unsigned short v[8];
#pragma unroll
    for (int j = 0; j < 8; ++j)
        v[j] = f2bf(xb[(size_t)j * HOUT * WOUT]);

    uint4 pack;
    pack.x = (unsigned)v[0] | ((unsigned)v[1] << 16);
    pack.y = (unsigned)v[2] | ((unsigned)v[3] << 16);
    pack.z = (unsigned)v[4] | ((unsigned)v[5] << 16);
    pack.w = (unsigned)v[6] | ((unsigned)v[7] << 16);

    *(uint4*)(xt + (size_t)((h + 1) * HPAD + (w + 1)) * 2048 + b * CIN + cg * 8) = pack;
}

// W pre-pass: re-layout W[s][k][c_out] fp32 into MFMA B-fragment order bf16:
//   Wt[(s*9 + t)*64 + lane] = uint4 = 8 bf16 {W[(8q+j)*9+t][n] : j=0..7},
//   lane = q*16+n. Also bsum[s][n] = bias[s] * colsum_k(W[s][k][n]) in fp32.
// Block = one site, 576 threads (9 waves = 9 taps). 8 loads/thread, full-line
// coalesced (per instr: 4 rows x 64B); 2.3M threads -> latency hidden by TLP.
__global__ __launch_bounds__(576) void wprep_kernel(const float* __restrict__ Wg,
                                                    const float* __restrict__ bias,
                                                    uint4* __restrict__ wt,
                                                    float* __restrict__ bsum) {
    __shared__ float red[9][16];
    int s    = blockIdx.x;
    int t    = threadIdx.x >> 6;     // tap 0..8
    int lane = threadIdx.x & 63;
    int q = lane >> 4, n = lane & 15;

    const float* wb = Wg + (size_t)s * (KTOT * COUT) + (size_t)((8 * q) * 9 + t) * COUT + n;
    float w[8];
#pragma unroll
    for (int j = 0; j < 8; ++j)
        w[j] = wb[(size_t)j * 9 * COUT];

    float csum = 0.f;
    unsigned short h[8];
#pragma unroll
    for (int j = 0; j < 8; ++j) { csum += w[j]; h[j] = f2bf(w[j]); }

    uint4 pack;
    pack.x = (unsigned)h[0] | ((unsigned)h[1] << 16);
    pack.y = (unsigned)h[2] | ((unsigned)h[3] << 16);
    pack.z = (unsigned)h[4] | ((unsigned)h[5] << 16);
    pack.w = (unsigned)h[6] | ((unsigned)h[7] << 16);
    wt[(size_t)(s * 9 + t) * 64 + lane] = pack;

    // colsum: reduce over q (shfl), then over taps (LDS)
    csum += __shfl_xor(csum, 16, 64);
    csum += __shfl_xor(csum, 32, 64);
    if (lane < 16) red[t][n] = csum;
    __syncthreads();
    if (threadIdx.x < 16) {
        float tot = 0.f;
#pragma unroll
        for (int tt = 0; tt < 9; ++tt) tot += red[tt][threadIdx.x];
        bsum[s * COUT + threadIdx.x] = bias[s] * tot;
    }
}

// Main kernel. Block = 16 consecutive sites x 16 batches (quarter). Grid 1024.
// The 4 batch-quarter blocks of a site-group get ids == lo (mod 8) within a
// 32-id window -> same XCD -> Wt HBM-fetched once, 3 L2 hits.
// Per site: 9 B-frag 16B loads (Wt) + 9 A-frag 16B loads (Xt) + 9 MFMA + 1
// bsum dword. No scalar gathers, no f2bf, no csum (R3 failure mode removed).
__global__ __launch_bounds__(256, 4) void varconv_kernel(const unsigned short* __restrict__ xt,
                                                         const uint4* __restrict__ wt,
                                                         const float* __restrict__ bsum,
                                                         float* __restrict__ out) {
    __shared__ float lds[16 * 16 * 16];   // [c][sl][b-slots], 16 KB

    int id = blockIdx.x;
    int lo = id & 7;                       // XCD
    int q4 = (id >> 3) & 3;                // batch quarter
    int g  = ((id >> 5) << 3) | lo;        // site-group 0..255
    int s0 = g * 16;
    int y  = s0 >> 6;
    int x0 = s0 & 63;
    int B0 = q4 * 16;

    int lane = threadIdx.x & 63, wv = threadIdx.x >> 6;
    int q = lane >> 4;          // quad
    int n = lane & 15;          // = c_out (B/D), = b-within-tile (A)

#pragma unroll
    for (int i = 0; i < 4; ++i) {
        int sl = wv * 4 + i;
        int s  = s0 + sl;
        int x  = x0 + sl;

        // --- B fragments: 9 contiguous 16B loads/lane ---
        const uint4* wf = wt + (size_t)s * 9 * 64 + lane;
        short8 bf[9];
#pragma unroll
        for (int t = 0; t < 9; ++t)
            bf[t] = *(const short8*)(wf + t * 64);

        float badd = bsum[s * COUT + n];   // bias[s]*colsum(W_s)[n]

        // --- A fragments: 9 contiguous-1KB-per-wave loads ---
        const unsigned short* ab = xt + (size_t)(B0 + n) * CIN + q * 8;
        short8 af[9];
#pragma unroll
        for (int t = 0; t < 9; ++t) {
            const int cy = t / 3, cx = t % 3;
            af[t] = *(const short8*)(ab + (size_t)((y + cy) * HPAD + (x + cx)) * 2048);
        }

        floatx4 acc = {0.f, 0.f, 0.f, 0.f};
#pragma unroll
        for (int t = 0; t < 9; ++t)
            acc = __builtin_amdgcn_mfma_f32_16x16x32_bf16(af[t], bf[t], acc, 0, 0, 0);

        // D: col = n = c_out, row(b local) = 4q+r. Slot-XOR for conflict-free b128.
        int slot = q ^ (n & 3);
        floatx4 v = {acc[0] + badd, acc[1] + badd, acc[2] + badd, acc[3] + badd};
        *(floatx4*)&lds[n * 256 + sl * 16 + slot * 4] = v;
    }

    __syncthreads();

    // --- epilogue: full-line coalesced writes (4 lanes = one 64B line) ---
    int c   = lane >> 2;     // 0..15
    int slg = lane & 3;      // 0..3
#pragma unroll
    for (int i2 = 0; i2 < 4; ++i2) {
        int ib   = wv * 4 + i2;             // local b 0..15
        int slot = (ib >> 2) ^ (c & 3);
        float o0[4];
#pragma unroll
        for (int e = 0; e < 4; ++e)
            o0[e] = lds[c * 256 + (slg * 4 + e) * 16 + slot * 4 + (ib & 3)];
        floatx4 o = {o0[0], o0[1], o0[2], o0[3]};
        *(floatx4*)(out + ((size_t)((B0 + ib) * COUT + c)) * SLOC + s0 + slg * 4) = o;
    }
}

extern "C" void kernel_launch(void* const* d_in, const int* in_sizes, int n_in,
                              void* d_out, int out_size, void* d_ws, size_t ws_size,
                              hipStream_t stream) {
    const float* X    = (const float*)d_in[0];   // [64][32][64][64] fp32
    const float* Wg   = (const float*)d_in[1];   // [4096][288][16] fp32
    const float* bias = (const float*)d_in[2];   // [4096] fp32
    float* out = (float*)d_out;                  // [64][16][4096] fp32

    // Workspace layout:
    //   xt   : 66*66*64*32*2              = 17,842,176 B
    //   wt   : 4096*9*64*16               = 37,748,736 B
    //   bsum : 4096*16*4                  =    262,144 B   (total ~53.3 MB)
    unsigned short* xt = (unsigned short*)d_ws;
    uint4* wt   = (uint4*)((char*)d_ws + 17842176);
    float* bsum = (float*)((char*)d_ws + 17842176 + 37748736);

    zero_border_kernel<<<260, 256, 0, stream>>>(xt);
    transpose_kernel<<<dim3(64, 64), 256, 0, stream>>>(X, xt);
    wprep_kernel<<<SLOC, 576, 0, stream>>>(Wg, bias, wt, bsum);
    varconv_kernel<<<1024, 256, 0, stream>>>(xt, wt, bsum, out);
}